// Round 2
// baseline (4303.374 us; speedup 1.0000x reference)
//
#include <hip/hip_runtime.h>
#include <math.h>

// ---------------------------------------------------------------------------
// CapsuleNet forward, fp32 correctness-first implementation.
// All intermediates live in static __device__ globals (d_ws proved too small
// in R0 -> GPU fault). ~308 MB total, allocated at module load.
// ---------------------------------------------------------------------------

__device__ float g_x1[256 * 256 * 400];    // conv1 out  [b][oc][20*20]  100 MB
__device__ float g_y2[9216 * 256];         // pc GEMM out [b*36+s][oc]   9.4 MB
__device__ float g_u[256 * 1152 * 8];      // squashed primary caps      9.4 MB
__device__ float g_WU[(size_t)256 * 1152 * 160];  // u_hat             188.7 MB
__device__ float g_ssum[3 * 256 * 160];    // pre-squash class sums
__device__ float g_v[3 * 256 * 160];       // v0, v1, v2
__device__ float g_h1[256 * 512];
__device__ float g_h2[256 * 1024];

// ---------------- zero the atomic accumulators ----------------
__global__ __launch_bounds__(256) void zero_ssum_k() {
  int i = blockIdx.x * 256 + threadIdx.x;
  if (i < 3 * 256 * 160) g_ssum[i] = 0.f;
}

// ---------------- conv1 + relu ----------------
__global__ __launch_bounds__(256) void conv1_relu_k(
    const float* __restrict__ in, const float* __restrict__ w,
    const float* __restrict__ bias) {
  __shared__ float in_s[784];      // 28x28 image
  __shared__ float w_s[64 * 81];   // 64-oc weight chunk
  int b = blockIdx.x;
  int oc0 = blockIdx.y * 64;
  int t = threadIdx.x;
  for (int i = t; i < 784; i += 256) in_s[i] = in[b * 784 + i];
  for (int i = t; i < 64 * 81; i += 256) w_s[i] = w[oc0 * 81 + i];
  __syncthreads();
  for (int oi = t; oi < 64 * 400; oi += 256) {
    int ocl = oi / 400;
    int sp = oi - ocl * 400;
    int oy = sp / 20;
    int ox = sp - oy * 20;
    float acc = bias[oc0 + ocl];
    const float* wr = &w_s[ocl * 81];
#pragma unroll
    for (int ky = 0; ky < 9; ky++) {
      const float* ir = &in_s[(oy + ky) * 28 + ox];
#pragma unroll
      for (int kx = 0; kx < 9; kx++) acc = fmaf(ir[kx], wr[ky * 9 + kx], acc);
    }
    g_x1[(size_t)(b * 256 + oc0 + ocl) * 400 + sp] = fmaxf(acc, 0.0f);
  }
}

// ---------------- pc conv as tiled GEMM ----------------
// C[m][n] = sum_k A[m][k] * W[n][k],  M=9216, N=256, K=20736
// A[m][k] = x1[b, ic, 2*oy+ky, 2*ox+kx] (im2col on the fly)
__global__ __launch_bounds__(256) void pc_gemm_k(
    const float* __restrict__ w, const float* __restrict__ bias) {
  __shared__ float A_s[16][68];
  __shared__ float B_s[16][68];
  int t = threadIdx.x;
  int n0 = blockIdx.x * 64;
  int m0 = blockIdx.y * 64;

  // A-load mapping: element (klocal = (t>>6)+4j, mlocal = t&63)
  int ml = t & 63;
  int kw = t >> 6;
  int m = m0 + ml;
  int bb = m / 36;
  int s = m - bb * 36;
  int oy = s / 6;
  int ox = s - oy * 6;
  const float* xbase = g_x1 + (size_t)bb * 102400 + oy * 40 + ox * 2;

  // B-load mapping: float4 at row n0+(t>>2), cols k0+((4t)&15)..+3
  int nl4 = t >> 2;
  int bk = (4 * t) & 15;
  const float* wbase = w + (size_t)(n0 + nl4) * 20736 + bk;

  float acc[4][4] = {};
  float a_pref[4];
  float4 b_pref;

#pragma unroll
  for (int j = 0; j < 4; j++) {
    int k = kw + 4 * j;
    int ic = k / 81;
    int r = k - ic * 81;
    int ky = r / 9;
    int kx = r - ky * 9;
    a_pref[j] = xbase[ic * 400 + ky * 20 + kx];
  }
  b_pref = *(const float4*)(wbase);

  int tm = t & 15, tn = t >> 4;

  for (int k0 = 0; k0 < 20736; k0 += 16) {
    __syncthreads();
#pragma unroll
    for (int j = 0; j < 4; j++) A_s[kw + 4 * j][ml] = a_pref[j];
    B_s[bk + 0][nl4] = b_pref.x;
    B_s[bk + 1][nl4] = b_pref.y;
    B_s[bk + 2][nl4] = b_pref.z;
    B_s[bk + 3][nl4] = b_pref.w;
    __syncthreads();
    if (k0 + 16 < 20736) {
#pragma unroll
      for (int j = 0; j < 4; j++) {
        int k = k0 + 16 + kw + 4 * j;
        int ic = k / 81;
        int r = k - ic * 81;
        int ky = r / 9;
        int kx = r - ky * 9;
        a_pref[j] = xbase[ic * 400 + ky * 20 + kx];
      }
      b_pref = *(const float4*)(wbase + k0 + 16);
    }
#pragma unroll
    for (int kk = 0; kk < 16; kk++) {
      float4 av = *(const float4*)&A_s[kk][4 * tm];
      float4 bv = *(const float4*)&B_s[kk][4 * tn];
      float a[4] = {av.x, av.y, av.z, av.w};
      float bq[4] = {bv.x, bv.y, bv.z, bv.w};
#pragma unroll
      for (int i = 0; i < 4; i++)
#pragma unroll
        for (int jj = 0; jj < 4; jj++)
          acc[i][jj] = fmaf(a[i], bq[jj], acc[i][jj]);
    }
  }
#pragma unroll
  for (int i = 0; i < 4; i++) {
    int mrow = m0 + 4 * tm + i;
    float4 o;
    o.x = acc[i][0] + bias[n0 + 4 * tn + 0];
    o.y = acc[i][1] + bias[n0 + 4 * tn + 1];
    o.z = acc[i][2] + bias[n0 + 4 * tn + 2];
    o.w = acc[i][3] + bias[n0 + 4 * tn + 3];
    *(float4*)&g_y2[(size_t)mrow * 256 + n0 + 4 * tn] = o;
  }
}

// ---------------- squash primary capsules ----------------
__global__ __launch_bounds__(256) void squash_u_k() {
  int gid = blockIdx.x * 256 + threadIdx.x;  // B*1152
  if (gid >= 256 * 1152) return;
  int b = gid / 1152;
  int n = gid - b * 1152;
  int g = n / 36;
  int s = n - g * 36;
  const float* base = g_y2 + (size_t)(b * 36 + s) * 256 + g;
  float x[8];
  float sq = 0.f;
#pragma unroll
  for (int p = 0; p < 8; p++) {
    x[p] = base[p * 32];
    sq = fmaf(x[p], x[p], sq);
  }
  float scale = (sq / (1.f + sq)) * rsqrtf(sq + 1e-7f);
  float* uo = g_u + (size_t)gid * 8;
#pragma unroll
  for (int p = 0; p < 8; p++) uo[p] = x[p] * scale;
}

// ---------------- WU einsum ----------------
// WU[b][n][cd] = sum_p W[n][cd][p] * u[b][n][p]
__global__ __launch_bounds__(256) void wu_k(const float* __restrict__ W) {
  __shared__ float W_s[8][161];   // [p][cd]
  __shared__ float u_s[32][8];
  int n = blockIdx.x;      // 1152
  int b0 = blockIdx.y * 32;
  int t = threadIdx.x;
  const float* Wn = W + (size_t)n * 1280;
  for (int i = t; i < 1280; i += 256) {
    int cd = i >> 3, p = i & 7;
    W_s[p][cd] = Wn[i];
  }
  {
    int bl = t >> 3, p = t & 7;
    u_s[bl][p] = g_u[(size_t)(b0 + bl) * 9216 + n * 8 + p];
  }
  __syncthreads();
#pragma unroll
  for (int i = 0; i < 20; i++) {
    int idx = t + 256 * i;   // 0..5119 over (bl, cd)
    int bl = idx / 160;
    int cd = idx - bl * 160;
    float acc = 0.f;
#pragma unroll
    for (int p = 0; p < 8; p++) acc = fmaf(u_s[bl][p], W_s[p][cd], acc);
    g_WU[((size_t)(b0 + bl) * 1152 + n) * 160 + cd] = acc;
  }
}

// ---------------- iter0 reduction: ssum0 = 0.1 * sum_n WU ----------------
__global__ __launch_bounds__(256) void red0_k() {
  int b = blockIdx.x;
  int chunk = blockIdx.y;  // 8 chunks of 144 n
  int t = threadIdx.x;
  if (t >= 160) return;
  const float* base = g_WU + ((size_t)b * 1152 + chunk * 144) * 160 + t;
  float acc = 0.f;
  for (int n = 0; n < 144; n++) acc += base[(size_t)n * 160];
  atomicAdd(&g_ssum[b * 160 + t], 0.1f * acc);
}

// ---------------- squash of class capsules (+ optional clf) ----------------
__global__ void squash_v_k(int slot, float* __restrict__ clf, int write_clf) {
  int b = blockIdx.x;
  int c = threadIdx.x;  // block 64, active < 10
  if (c >= 10) return;
  const float* s = g_ssum + slot * 40960 + b * 160 + c * 16;
  float sq = 0.f;
#pragma unroll
  for (int d = 0; d < 16; d++) sq = fmaf(s[d], s[d], sq);
  float scale = (sq / (1.f + sq)) * rsqrtf(sq + 1e-7f);
  float* vo = g_v + slot * 40960 + b * 160 + c * 16;
#pragma unroll
  for (int d = 0; d < 16; d++) vo[d] = s[d] * scale;
  if (write_clf) clf[b * 10 + c] = scale * sqrtf(sq);
}

// ---------------- routing iteration (IT=1 or 2) ----------------
// 16-lane groups; lane = d. Computes coupling for this iteration and
// accumulates ssum_out[b][c*16+d] = sum_n c_it[n][c] * WU[b][n][c*16+d].
template <int IT>
__global__ __launch_bounds__(256) void routing_iter_k() {
  int b = blockIdx.x;
  int nb = blockIdx.y;   // 8 -> n range [nb*144, nb*144+144)
  int t = threadIdx.x;
  int lane = t & 15;     // d
  int grp = t >> 4;      // 16 groups per block

  const float* v0 = g_v;                 // slot 0
  const float* v1 = g_v + 40960;         // slot 1
  float* ssum_out = g_ssum + IT * 40960;

  float v0r[10], v1r[10];
#pragma unroll
  for (int c = 0; c < 10; c++) v0r[c] = v0[b * 160 + c * 16 + lane];
  if (IT == 2) {
#pragma unroll
    for (int c = 0; c < 10; c++) v1r[c] = v1[b * 160 + c * 16 + lane];
  }

  float acc[10];
#pragma unroll
  for (int c = 0; c < 10; c++) acc[c] = 0.f;

  for (int ni = 0; ni < 9; ni++) {
    int n = nb * 144 + grp * 9 + ni;
    const float* row = g_WU + ((size_t)b * 1152 + n) * 160;
    float wu[10];
#pragma unroll
    for (int c = 0; c < 10; c++) wu[c] = row[c * 16 + lane];

    // dot0[c] = sum_d v0[c][d]*WU[n][c][d]  via 16-lane butterfly
    float bij[10];
#pragma unroll
    for (int c = 0; c < 10; c++) {
      float x = v0r[c] * wu[c];
      x += __shfl_xor(x, 1);
      x += __shfl_xor(x, 2);
      x += __shfl_xor(x, 4);
      x += __shfl_xor(x, 8);
      bij[c] = 0.1f * x;   // b1 = 0 + c0(=0.1) * dot0
    }

    if (IT == 2) {
      // c1 = softmax(b1)
      float mx = bij[0];
#pragma unroll
      for (int c = 1; c < 10; c++) mx = fmaxf(mx, bij[c]);
      float e[10], ssum = 0.f;
#pragma unroll
      for (int c = 0; c < 10; c++) {
        e[c] = __expf(bij[c] - mx);
        ssum += e[c];
      }
      float inv = 1.f / ssum;
      // dot1[c] and b2 = b1 + c1*dot1
#pragma unroll
      for (int c = 0; c < 10; c++) {
        float x = v1r[c] * wu[c];
        x += __shfl_xor(x, 1);
        x += __shfl_xor(x, 2);
        x += __shfl_xor(x, 4);
        x += __shfl_xor(x, 8);
        bij[c] = bij[c] + (e[c] * inv) * x;
      }
    }

    // final coupling for this iteration = softmax(bij)
    float mx = bij[0];
#pragma unroll
    for (int c = 1; c < 10; c++) mx = fmaxf(mx, bij[c]);
    float e[10], ssum = 0.f;
#pragma unroll
    for (int c = 0; c < 10; c++) {
      e[c] = __expf(bij[c] - mx);
      ssum += e[c];
    }
    float inv = 1.f / ssum;
#pragma unroll
    for (int c = 0; c < 10; c++) acc[c] = fmaf(e[c] * inv, wu[c], acc[c]);
  }
#pragma unroll
  for (int c = 0; c < 10; c++)
    atomicAdd(&ssum_out[b * 160 + c * 16 + lane], acc[c]);
}

// ---------------- decoder ----------------
__global__ __launch_bounds__(256) void dec1_k(const int* __restrict__ labels,
                                              const float* __restrict__ w1,
                                              const float* __restrict__ b1) {
  int b = blockIdx.x;
  int t = threadIdx.x;
  int lab = labels[b];
  const float* vv = g_v + 2 * 40960 + b * 160 + lab * 16;
#pragma unroll
  for (int r = 0; r < 2; r++) {
    int j = t + r * 256;
    float acc = b1[j];
#pragma unroll
    for (int d = 0; d < 16; d++)
      acc = fmaf(vv[d], w1[(size_t)(lab * 16 + d) * 512 + j], acc);
    g_h1[b * 512 + j] = fmaxf(acc, 0.f);
  }
}

__global__ __launch_bounds__(256) void dec2_k(const float* __restrict__ w2,
                                              const float* __restrict__ b2) {
  int b = blockIdx.x;
  int t = threadIdx.x;
  float acc[4] = {b2[t], b2[t + 256], b2[t + 512], b2[t + 768]};
  const float* hh = g_h1 + b * 512;
  for (int k = 0; k < 512; k++) {
    float hv = hh[k];
    const float* wr = w2 + (size_t)k * 1024;
    acc[0] = fmaf(hv, wr[t], acc[0]);
    acc[1] = fmaf(hv, wr[t + 256], acc[1]);
    acc[2] = fmaf(hv, wr[t + 512], acc[2]);
    acc[3] = fmaf(hv, wr[t + 768], acc[3]);
  }
  g_h2[b * 1024 + t] = fmaxf(acc[0], 0.f);
  g_h2[b * 1024 + t + 256] = fmaxf(acc[1], 0.f);
  g_h2[b * 1024 + t + 512] = fmaxf(acc[2], 0.f);
  g_h2[b * 1024 + t + 768] = fmaxf(acc[3], 0.f);
}

__global__ __launch_bounds__(256) void dec3_k(const float* __restrict__ w3,
                                              const float* __restrict__ b3,
                                              float* __restrict__ out) {
  int b = blockIdx.x;
  int t = threadIdx.x;
  float acc[4];
#pragma unroll
  for (int jj = 0; jj < 4; jj++) {
    int j = t + 256 * jj;
    acc[jj] = (j < 784) ? b3[j] : 0.f;
  }
  const float* hh = g_h2 + b * 1024;
  for (int k = 0; k < 1024; k++) {
    float hv = hh[k];
    const float* wr = w3 + (size_t)k * 784;
#pragma unroll
    for (int jj = 0; jj < 4; jj++) {
      int j = t + 256 * jj;
      if (j < 784) acc[jj] = fmaf(hv, wr[j], acc[jj]);
    }
  }
#pragma unroll
  for (int jj = 0; jj < 4; jj++) {
    int j = t + 256 * jj;
    if (j < 784) out[2560 + b * 784 + j] = 1.f / (1.f + __expf(-acc[jj]));
  }
}

// ---------------------------------------------------------------------------
extern "C" void kernel_launch(void* const* d_in, const int* in_sizes, int n_in,
                              void* d_out, int out_size, void* d_ws,
                              size_t ws_size, hipStream_t stream) {
  const float* inputs = (const float*)d_in[0];
  const int* labels = (const int*)d_in[1];
  const float* conv1_w = (const float*)d_in[2];
  const float* conv1_b = (const float*)d_in[3];
  const float* pc_w = (const float*)d_in[4];
  const float* pc_b = (const float*)d_in[5];
  const float* rw = (const float*)d_in[6];
  const float* dw1 = (const float*)d_in[7];
  const float* db1 = (const float*)d_in[8];
  const float* dw2 = (const float*)d_in[9];
  const float* db2 = (const float*)d_in[10];
  const float* dw3 = (const float*)d_in[11];
  const float* db3 = (const float*)d_in[12];
  float* out = (float*)d_out;
  (void)d_ws; (void)ws_size; (void)in_sizes; (void)n_in;

  zero_ssum_k<<<(3 * 256 * 160 + 255) / 256, 256, 0, stream>>>();
  conv1_relu_k<<<dim3(256, 4), 256, 0, stream>>>(inputs, conv1_w, conv1_b);
  pc_gemm_k<<<dim3(4, 144), 256, 0, stream>>>(pc_w, pc_b);
  squash_u_k<<<1152, 256, 0, stream>>>();
  wu_k<<<dim3(1152, 8), 256, 0, stream>>>(rw);
  red0_k<<<dim3(256, 8), 256, 0, stream>>>();
  squash_v_k<<<256, 64, 0, stream>>>(0, nullptr, 0);
  routing_iter_k<1><<<dim3(256, 8), 256, 0, stream>>>();
  squash_v_k<<<256, 64, 0, stream>>>(1, nullptr, 0);
  routing_iter_k<2><<<dim3(256, 8), 256, 0, stream>>>();
  squash_v_k<<<256, 64, 0, stream>>>(2, out, 1);
  dec1_k<<<256, 256, 0, stream>>>(labels, dw1, db1);
  dec2_k<<<256, 256, 0, stream>>>(dw2, db2);
  dec3_k<<<256, 256, 0, stream>>>(dw3, db3, out);
}

// Round 3
// 2764.452 us; speedup vs baseline: 1.5567x; 1.5567x over previous
//
#include <hip/hip_runtime.h>
#include <math.h>

// ---------------------------------------------------------------------------
// CapsuleNet forward. R2: pc-conv GEMM moved to bf16 MFMA (fp32 accumulate).
// conv1 emits bf16 x1; pc_w converted to bf16 per launch; K split 4 ways into
// fp32 partial buffers reduced in squash_u. Everything else fp32 as in R1.
// ---------------------------------------------------------------------------

typedef unsigned short u16;
typedef short bf16x8 __attribute__((ext_vector_type(8)));
typedef float f32x4 __attribute__((ext_vector_type(4)));

#define PS 2359296  // 9216*256, one y2 partial buffer

__device__ u16 g_x1b[256 * 256 * 400];          // conv1 out, bf16 bits (52 MB)
__device__ u16 g_wb[256 * 20736];               // pc_w bf16 (10.6 MB)
__device__ float g_y2p[4 * PS];                 // pc GEMM K-partials (37.7 MB)
__device__ float g_u[256 * 1152 * 8];           // squashed primary caps
__device__ float g_WU[(size_t)256 * 1152 * 160];// u_hat (188.7 MB)
__device__ float g_ssum[3 * 256 * 160];
__device__ float g_v[3 * 256 * 160];
__device__ float g_h1[256 * 512];
__device__ float g_h2[256 * 1024];

__device__ __forceinline__ u16 f2bf(float f) {
  union { float f; unsigned u; } v; v.f = f;
  unsigned r = (v.u + 0x7FFFu + ((v.u >> 16) & 1u)) >> 16;  // RNE
  return (u16)r;
}

// ---------------- zero the atomic accumulators ----------------
__global__ __launch_bounds__(256) void zero_ssum_k() {
  int i = blockIdx.x * 256 + threadIdx.x;
  if (i < 3 * 256 * 160) g_ssum[i] = 0.f;
}

// ---------------- pc_w fp32 -> bf16 ----------------
__global__ __launch_bounds__(256) void wconv_k(const float* __restrict__ w) {
  int i = (blockIdx.x * 256 + threadIdx.x) * 4;  // 256*20736 elems, /4
  if (i >= 256 * 20736) return;
  float4 v = *(const float4*)(w + i);
  g_wb[i + 0] = f2bf(v.x);
  g_wb[i + 1] = f2bf(v.y);
  g_wb[i + 2] = f2bf(v.z);
  g_wb[i + 3] = f2bf(v.w);
}

// ---------------- conv1 + relu -> bf16 ----------------
__global__ __launch_bounds__(256) void conv1_relu_k(
    const float* __restrict__ in, const float* __restrict__ w,
    const float* __restrict__ bias) {
  __shared__ float in_s[784];
  __shared__ float w_s[64 * 81];
  int b = blockIdx.x;
  int oc0 = blockIdx.y * 64;
  int t = threadIdx.x;
  for (int i = t; i < 784; i += 256) in_s[i] = in[b * 784 + i];
  for (int i = t; i < 64 * 81; i += 256) w_s[i] = w[oc0 * 81 + i];
  __syncthreads();
  for (int oi = t; oi < 64 * 400; oi += 256) {
    int ocl = oi / 400;
    int sp = oi - ocl * 400;
    int oy = sp / 20;
    int ox = sp - oy * 20;
    float acc = bias[oc0 + ocl];
    const float* wr = &w_s[ocl * 81];
#pragma unroll
    for (int ky = 0; ky < 9; ky++) {
      const float* ir = &in_s[(oy + ky) * 28 + ox];
#pragma unroll
      for (int kx = 0; kx < 9; kx++) acc = fmaf(ir[kx], wr[ky * 9 + kx], acc);
    }
    g_x1b[(size_t)(b * 256 + oc0 + ocl) * 400 + sp] = f2bf(fmaxf(acc, 0.0f));
  }
}

// ---------------- pc conv: bf16 MFMA GEMM ----------------
// C[m][n] = sum_k A[m][k]*W[n][k]; M=9216,N=256,K=20736. A = im2col(x1b).
// Grid (2,144,4): n0=bx*128, m0=by*64, K-range [bz*5184, +5184).
// Block 256 = 4 waves; wave w: rows m0+(w&1)*32, cols n0+(w>>1)*64.
__global__ __launch_bounds__(256) void pc_mfma_k(float* __restrict__ y2p) {
  __shared__ u16 As[64 * 72];  // 64 rows x BK=64, padded stride 72
  int t = threadIdx.x;
  int n0 = blockIdx.x * 128;
  int m0 = blockIdx.y * 64;
  int ks0 = blockIdx.z * 5184;
  float* outp = y2p + (size_t)blockIdx.z * PS;

  int w = t >> 6, l = t & 63, quad = l >> 4, c15 = l & 15;
  int wm = w & 1, wn = w >> 1;

  // ---- A-gather mapping: thread -> (row r, k-chunk wq*16) ----
  int r = t & 63;
  int wq = t >> 6;
  int m = m0 + r;
  int bb = m / 36;
  int sp = m - bb * 36;
  int oy = sp / 6;
  int ox = sp - oy * 6;
  int fixed = bb * 102400 + 40 * oy + 2 * ox;
  int ks = ks0 + wq * 16;
  int ic = ks / 81;
  int rr = ks - ic * 81;
  int ky = rr / 9;
  int kx = rr - ky * 9;

  f32x4 acc[2][4];
#pragma unroll
  for (int i = 0; i < 2; i++)
#pragma unroll
    for (int j = 0; j < 4; j++) acc[i][j] = (f32x4){0.f, 0.f, 0.f, 0.f};

  u16 ag[16];
  // gather stage 0
  {
    int lkx = kx, lky = ky, loff = fixed + ic * 400 + ky * 20 + kx;
#pragma unroll
    for (int j = 0; j < 16; j++) {
      ag[j] = g_x1b[loff];
      lkx++; loff++;
      if (lkx == 9) { lkx = 0; loff += 11; lky++; if (lky == 9) { lky = 0; loff += 220; } }
    }
  }

  for (int st = 0; st < 81; st++) {
    __syncthreads();
    {
      bf16x8 p0, p1;
#pragma unroll
      for (int j = 0; j < 8; j++) { p0[j] = (short)ag[j]; p1[j] = (short)ag[j + 8]; }
      *(bf16x8*)&As[r * 72 + wq * 16] = p0;
      *(bf16x8*)&As[r * 72 + wq * 16 + 8] = p1;
    }
    __syncthreads();
    // advance gather state by 64 and prefetch next stage
    if (st < 80) {
      kx += 1; if (kx >= 9) { kx -= 9; ky += 1; }
      ky += 7; if (ky >= 9) { ky -= 9; ic += 1; }
      int lkx = kx, lky = ky, loff = fixed + ic * 400 + ky * 20 + kx;
#pragma unroll
      for (int j = 0; j < 16; j++) {
        ag[j] = g_x1b[loff];
        lkx++; loff++;
        if (lkx == 9) { lkx = 0; loff += 11; lky++; if (lky == 9) { lky = 0; loff += 220; } }
      }
    }
    int k0g = ks0 + st * 64;
#pragma unroll
    for (int kk = 0; kk < 2; kk++) {
      bf16x8 bf[4];
#pragma unroll
      for (int jn = 0; jn < 4; jn++) {
        int nrow = n0 + wn * 64 + jn * 16 + c15;
        bf[jn] = *(const bf16x8*)&g_wb[(size_t)nrow * 20736 + k0g + kk * 32 + quad * 8];
      }
#pragma unroll
      for (int i = 0; i < 2; i++) {
        bf16x8 af = *(const bf16x8*)&As[(wm * 32 + i * 16 + c15) * 72 + kk * 32 + quad * 8];
#pragma unroll
        for (int jn = 0; jn < 4; jn++)
          acc[i][jn] = __builtin_amdgcn_mfma_f32_16x16x32_bf16(af, bf[jn], acc[i][jn], 0, 0, 0);
      }
    }
  }
  // epilogue: C/D map col=lane&15, row=quad*4+reg
#pragma unroll
  for (int i = 0; i < 2; i++)
#pragma unroll
    for (int jn = 0; jn < 4; jn++) {
      int col = n0 + wn * 64 + jn * 16 + c15;
#pragma unroll
      for (int rg = 0; rg < 4; rg++) {
        int row = m0 + wm * 32 + i * 16 + quad * 4 + rg;
        outp[(size_t)row * 256 + col] = acc[i][jn][rg];
      }
    }
}

// ---------------- squash primary capsules (sums 4 K-partials + bias) -------
__global__ __launch_bounds__(256) void squash_u_k(const float* __restrict__ pcb) {
  int gid = blockIdx.x * 256 + threadIdx.x;  // B*1152
  if (gid >= 256 * 1152) return;
  int b = gid / 1152;
  int n = gid - b * 1152;
  int g = n / 36;
  int s = n - g * 36;
  const float* base = g_y2p + (size_t)(b * 36 + s) * 256 + g;
  float x[8];
  float sq = 0.f;
#pragma unroll
  for (int p = 0; p < 8; p++) {
    float v = pcb[p * 32 + g] + base[p * 32] + base[PS + p * 32] +
              base[2 * PS + p * 32] + base[3 * PS + p * 32];
    x[p] = v;
    sq = fmaf(v, v, sq);
  }
  float scale = (sq / (1.f + sq)) * rsqrtf(sq + 1e-7f);
  float* uo = g_u + (size_t)gid * 8;
#pragma unroll
  for (int p = 0; p < 8; p++) uo[p] = x[p] * scale;
}

// ---------------- WU einsum ----------------
__global__ __launch_bounds__(256) void wu_k(const float* __restrict__ W) {
  __shared__ float W_s[8][161];
  __shared__ float u_s[32][8];
  int n = blockIdx.x;
  int b0 = blockIdx.y * 32;
  int t = threadIdx.x;
  const float* Wn = W + (size_t)n * 1280;
  for (int i = t; i < 1280; i += 256) {
    int cd = i >> 3, p = i & 7;
    W_s[p][cd] = Wn[i];
  }
  {
    int bl = t >> 3, p = t & 7;
    u_s[bl][p] = g_u[(size_t)(b0 + bl) * 9216 + n * 8 + p];
  }
  __syncthreads();
#pragma unroll
  for (int i = 0; i < 20; i++) {
    int idx = t + 256 * i;
    int bl = idx / 160;
    int cd = idx - bl * 160;
    float acc = 0.f;
#pragma unroll
    for (int p = 0; p < 8; p++) acc = fmaf(u_s[bl][p], W_s[p][cd], acc);
    g_WU[((size_t)(b0 + bl) * 1152 + n) * 160 + cd] = acc;
  }
}

// ---------------- iter0 reduction ----------------
__global__ __launch_bounds__(256) void red0_k() {
  int b = blockIdx.x;
  int chunk = blockIdx.y;
  int t = threadIdx.x;
  if (t >= 160) return;
  const float* base = g_WU + ((size_t)b * 1152 + chunk * 144) * 160 + t;
  float acc = 0.f;
  for (int n = 0; n < 144; n++) acc += base[(size_t)n * 160];
  atomicAdd(&g_ssum[b * 160 + t], 0.1f * acc);
}

// ---------------- squash of class capsules ----------------
__global__ void squash_v_k(int slot, float* __restrict__ clf, int write_clf) {
  int b = blockIdx.x;
  int c = threadIdx.x;
  if (c >= 10) return;
  const float* s = g_ssum + slot * 40960 + b * 160 + c * 16;
  float sq = 0.f;
#pragma unroll
  for (int d = 0; d < 16; d++) sq = fmaf(s[d], s[d], sq);
  float scale = (sq / (1.f + sq)) * rsqrtf(sq + 1e-7f);
  float* vo = g_v + slot * 40960 + b * 160 + c * 16;
#pragma unroll
  for (int d = 0; d < 16; d++) vo[d] = s[d] * scale;
  if (write_clf) clf[b * 10 + c] = scale * sqrtf(sq);
}

// ---------------- routing iteration ----------------
template <int IT>
__global__ __launch_bounds__(256) void routing_iter_k() {
  int b = blockIdx.x;
  int nb = blockIdx.y;
  int t = threadIdx.x;
  int lane = t & 15;
  int grp = t >> 4;

  const float* v0 = g_v;
  const float* v1 = g_v + 40960;
  float* ssum_out = g_ssum + IT * 40960;

  float v0r[10], v1r[10];
#pragma unroll
  for (int c = 0; c < 10; c++) v0r[c] = v0[b * 160 + c * 16 + lane];
  if (IT == 2) {
#pragma unroll
    for (int c = 0; c < 10; c++) v1r[c] = v1[b * 160 + c * 16 + lane];
  }

  float acc[10];
#pragma unroll
  for (int c = 0; c < 10; c++) acc[c] = 0.f;

  for (int ni = 0; ni < 9; ni++) {
    int n = nb * 144 + grp * 9 + ni;
    const float* row = g_WU + ((size_t)b * 1152 + n) * 160;
    float wu[10];
#pragma unroll
    for (int c = 0; c < 10; c++) wu[c] = row[c * 16 + lane];

    float bij[10];
#pragma unroll
    for (int c = 0; c < 10; c++) {
      float x = v0r[c] * wu[c];
      x += __shfl_xor(x, 1);
      x += __shfl_xor(x, 2);
      x += __shfl_xor(x, 4);
      x += __shfl_xor(x, 8);
      bij[c] = 0.1f * x;
    }

    if (IT == 2) {
      float mx = bij[0];
#pragma unroll
      for (int c = 1; c < 10; c++) mx = fmaxf(mx, bij[c]);
      float e[10], ssum = 0.f;
#pragma unroll
      for (int c = 0; c < 10; c++) {
        e[c] = __expf(bij[c] - mx);
        ssum += e[c];
      }
      float inv = 1.f / ssum;
#pragma unroll
      for (int c = 0; c < 10; c++) {
        float x = v1r[c] * wu[c];
        x += __shfl_xor(x, 1);
        x += __shfl_xor(x, 2);
        x += __shfl_xor(x, 4);
        x += __shfl_xor(x, 8);
        bij[c] = bij[c] + (e[c] * inv) * x;
      }
    }

    float mx = bij[0];
#pragma unroll
    for (int c = 1; c < 10; c++) mx = fmaxf(mx, bij[c]);
    float e[10], ssum = 0.f;
#pragma unroll
    for (int c = 0; c < 10; c++) {
      e[c] = __expf(bij[c] - mx);
      ssum += e[c];
    }
    float inv = 1.f / ssum;
#pragma unroll
    for (int c = 0; c < 10; c++) acc[c] = fmaf(e[c] * inv, wu[c], acc[c]);
  }
#pragma unroll
  for (int c = 0; c < 10; c++)
    atomicAdd(&ssum_out[b * 160 + c * 16 + lane], acc[c]);
}

// ---------------- decoder ----------------
__global__ __launch_bounds__(256) void dec1_k(const int* __restrict__ labels,
                                              const float* __restrict__ w1,
                                              const float* __restrict__ b1) {
  int b = blockIdx.x;
  int t = threadIdx.x;
  int lab = labels[b];
  const float* vv = g_v + 2 * 40960 + b * 160 + lab * 16;
#pragma unroll
  for (int r = 0; r < 2; r++) {
    int j = t + r * 256;
    float acc = b1[j];
#pragma unroll
    for (int d = 0; d < 16; d++)
      acc = fmaf(vv[d], w1[(size_t)(lab * 16 + d) * 512 + j], acc);
    g_h1[b * 512 + j] = fmaxf(acc, 0.f);
  }
}

__global__ __launch_bounds__(256) void dec2_k(const float* __restrict__ w2,
                                              const float* __restrict__ b2) {
  int b = blockIdx.x;
  int t = threadIdx.x;
  float acc[4] = {b2[t], b2[t + 256], b2[t + 512], b2[t + 768]};
  const float* hh = g_h1 + b * 512;
  for (int k = 0; k < 512; k++) {
    float hv = hh[k];
    const float* wr = w2 + (size_t)k * 1024;
    acc[0] = fmaf(hv, wr[t], acc[0]);
    acc[1] = fmaf(hv, wr[t + 256], acc[1]);
    acc[2] = fmaf(hv, wr[t + 512], acc[2]);
    acc[3] = fmaf(hv, wr[t + 768], acc[3]);
  }
  g_h2[b * 1024 + t] = fmaxf(acc[0], 0.f);
  g_h2[b * 1024 + t + 256] = fmaxf(acc[1], 0.f);
  g_h2[b * 1024 + t + 512] = fmaxf(acc[2], 0.f);
  g_h2[b * 1024 + t + 768] = fmaxf(acc[3], 0.f);
}

__global__ __launch_bounds__(256) void dec3_k(const float* __restrict__ w3,
                                              const float* __restrict__ b3,
                                              float* __restrict__ out) {
  int b = blockIdx.x;
  int t = threadIdx.x;
  float acc[4];
#pragma unroll
  for (int jj = 0; jj < 4; jj++) {
    int j = t + 256 * jj;
    acc[jj] = (j < 784) ? b3[j] : 0.f;
  }
  const float* hh = g_h2 + b * 1024;
  for (int k = 0; k < 1024; k++) {
    float hv = hh[k];
    const float* wr = w3 + (size_t)k * 784;
#pragma unroll
    for (int jj = 0; jj < 4; jj++) {
      int j = t + 256 * jj;
      if (j < 784) acc[jj] = fmaf(hv, wr[j], acc[jj]);
    }
  }
#pragma unroll
  for (int jj = 0; jj < 4; jj++) {
    int j = t + 256 * jj;
    if (j < 784) out[2560 + b * 784 + j] = 1.f / (1.f + __expf(-acc[jj]));
  }
}

// ---------------------------------------------------------------------------
extern "C" void kernel_launch(void* const* d_in, const int* in_sizes, int n_in,
                              void* d_out, int out_size, void* d_ws,
                              size_t ws_size, hipStream_t stream) {
  const float* inputs = (const float*)d_in[0];
  const int* labels = (const int*)d_in[1];
  const float* conv1_w = (const float*)d_in[2];
  const float* conv1_b = (const float*)d_in[3];
  const float* pc_w = (const float*)d_in[4];
  const float* pc_b = (const float*)d_in[5];
  const float* rw = (const float*)d_in[6];
  const float* dw1 = (const float*)d_in[7];
  const float* db1 = (const float*)d_in[8];
  const float* dw2 = (const float*)d_in[9];
  const float* db2 = (const float*)d_in[10];
  const float* dw3 = (const float*)d_in[11];
  const float* db3 = (const float*)d_in[12];
  float* out = (float*)d_out;
  (void)d_ws; (void)ws_size; (void)in_sizes; (void)n_in;

  float* y2p;
  hipGetSymbolAddress((void**)&y2p, HIP_SYMBOL(g_y2p));

  zero_ssum_k<<<(3 * 256 * 160 + 255) / 256, 256, 0, stream>>>();
  wconv_k<<<(256 * 20736 / 4 + 255) / 256, 256, 0, stream>>>(pc_w);
  conv1_relu_k<<<dim3(256, 4), 256, 0, stream>>>(inputs, conv1_w, conv1_b);
  pc_mfma_k<<<dim3(2, 144, 4), 256, 0, stream>>>(y2p);
  squash_u_k<<<1152, 256, 0, stream>>>(pc_b);
  wu_k<<<dim3(1152, 8), 256, 0, stream>>>(rw);
  red0_k<<<dim3(256, 8), 256, 0, stream>>>();
  squash_v_k<<<256, 64, 0, stream>>>(0, nullptr, 0);
  routing_iter_k<1><<<dim3(256, 8), 256, 0, stream>>>();
  squash_v_k<<<256, 64, 0, stream>>>(1, nullptr, 0);
  routing_iter_k<2><<<dim3(256, 8), 256, 0, stream>>>();
  squash_v_k<<<256, 64, 0, stream>>>(2, out, 1);
  dec1_k<<<256, 256, 0, stream>>>(labels, dw1, db1);
  dec2_k<<<256, 256, 0, stream>>>(dw2, db2);
  dec3_k<<<256, 256, 0, stream>>>(dw3, db3, out);
}

// Round 4
// 1453.243 us; speedup vs baseline: 2.9612x; 1.9023x over previous
//
#include <hip/hip_runtime.h>
#include <math.h>

// ---------------------------------------------------------------------------
// CapsuleNet forward. R3: decoder GEMMs restructured for parallelism
// (R2 profile: dec3 1332us at 0.77% VALUBusy, 1 block/CU latency-bound).
// pc-conv stays bf16 MFMA; rest fp32 as in R2.
// ---------------------------------------------------------------------------

typedef unsigned short u16;
typedef short bf16x8 __attribute__((ext_vector_type(8)));
typedef float f32x4 __attribute__((ext_vector_type(4)));

#define PS 2359296  // 9216*256, one y2 partial buffer

__device__ u16 g_x1b[256 * 256 * 400];          // conv1 out, bf16 bits (52 MB)
__device__ u16 g_wb[256 * 20736];               // pc_w bf16 (10.6 MB)
__device__ float g_y2p[4 * PS];                 // pc GEMM K-partials (37.7 MB)
__device__ float g_u[256 * 1152 * 8];           // squashed primary caps
__device__ float g_WU[(size_t)256 * 1152 * 160];// u_hat (188.7 MB)
__device__ float g_ssum[3 * 256 * 160];
__device__ float g_v[3 * 256 * 160];
__device__ float g_h1[256 * 512];
__device__ float g_h2[256 * 1024];

__device__ __forceinline__ u16 f2bf(float f) {
  union { float f; unsigned u; } v; v.f = f;
  unsigned r = (v.u + 0x7FFFu + ((v.u >> 16) & 1u)) >> 16;  // RNE
  return (u16)r;
}

// ---------------- zero the atomic accumulators ----------------
__global__ __launch_bounds__(256) void zero_ssum_k() {
  int i = blockIdx.x * 256 + threadIdx.x;
  if (i < 3 * 256 * 160) g_ssum[i] = 0.f;
}

// ---------------- pc_w fp32 -> bf16 ----------------
__global__ __launch_bounds__(256) void wconv_k(const float* __restrict__ w) {
  int i = (blockIdx.x * 256 + threadIdx.x) * 4;  // 256*20736 elems, /4
  if (i >= 256 * 20736) return;
  float4 v = *(const float4*)(w + i);
  g_wb[i + 0] = f2bf(v.x);
  g_wb[i + 1] = f2bf(v.y);
  g_wb[i + 2] = f2bf(v.z);
  g_wb[i + 3] = f2bf(v.w);
}

// ---------------- conv1 + relu -> bf16 ----------------
__global__ __launch_bounds__(256) void conv1_relu_k(
    const float* __restrict__ in, const float* __restrict__ w,
    const float* __restrict__ bias) {
  __shared__ float in_s[784];
  __shared__ float w_s[64 * 81];
  int b = blockIdx.x;
  int oc0 = blockIdx.y * 64;
  int t = threadIdx.x;
  for (int i = t; i < 784; i += 256) in_s[i] = in[b * 784 + i];
  for (int i = t; i < 64 * 81; i += 256) w_s[i] = w[oc0 * 81 + i];
  __syncthreads();
  for (int oi = t; oi < 64 * 400; oi += 256) {
    int ocl = oi / 400;
    int sp = oi - ocl * 400;
    int oy = sp / 20;
    int ox = sp - oy * 20;
    float acc = bias[oc0 + ocl];
    const float* wr = &w_s[ocl * 81];
#pragma unroll
    for (int ky = 0; ky < 9; ky++) {
      const float* ir = &in_s[(oy + ky) * 28 + ox];
#pragma unroll
      for (int kx = 0; kx < 9; kx++) acc = fmaf(ir[kx], wr[ky * 9 + kx], acc);
    }
    g_x1b[(size_t)(b * 256 + oc0 + ocl) * 400 + sp] = f2bf(fmaxf(acc, 0.0f));
  }
}

// ---------------- pc conv: bf16 MFMA GEMM ----------------
// C[m][n] = sum_k A[m][k]*W[n][k]; M=9216,N=256,K=20736. A = im2col(x1b).
// Grid (2,144,4): n0=bx*128, m0=by*64, K-range [bz*5184, +5184).
__global__ __launch_bounds__(256) void pc_mfma_k(float* __restrict__ y2p) {
  __shared__ u16 As[64 * 72];  // 64 rows x BK=64, padded stride 72
  int t = threadIdx.x;
  int n0 = blockIdx.x * 128;
  int m0 = blockIdx.y * 64;
  int ks0 = blockIdx.z * 5184;
  float* outp = y2p + (size_t)blockIdx.z * PS;

  int w = t >> 6, l = t & 63, quad = l >> 4, c15 = l & 15;
  int wm = w & 1, wn = w >> 1;

  int r = t & 63;
  int wq = t >> 6;
  int m = m0 + r;
  int bb = m / 36;
  int sp = m - bb * 36;
  int oy = sp / 6;
  int ox = sp - oy * 6;
  int fixed = bb * 102400 + 40 * oy + 2 * ox;
  int ks = ks0 + wq * 16;
  int ic = ks / 81;
  int rr = ks - ic * 81;
  int ky = rr / 9;
  int kx = rr - ky * 9;

  f32x4 acc[2][4];
#pragma unroll
  for (int i = 0; i < 2; i++)
#pragma unroll
    for (int j = 0; j < 4; j++) acc[i][j] = (f32x4){0.f, 0.f, 0.f, 0.f};

  u16 ag[16];
  {
    int lkx = kx, lky = ky, loff = fixed + ic * 400 + ky * 20 + kx;
#pragma unroll
    for (int j = 0; j < 16; j++) {
      ag[j] = g_x1b[loff];
      lkx++; loff++;
      if (lkx == 9) { lkx = 0; loff += 11; lky++; if (lky == 9) { lky = 0; loff += 220; } }
    }
  }

  for (int st = 0; st < 81; st++) {
    __syncthreads();
    {
      bf16x8 p0, p1;
#pragma unroll
      for (int j = 0; j < 8; j++) { p0[j] = (short)ag[j]; p1[j] = (short)ag[j + 8]; }
      *(bf16x8*)&As[r * 72 + wq * 16] = p0;
      *(bf16x8*)&As[r * 72 + wq * 16 + 8] = p1;
    }
    __syncthreads();
    if (st < 80) {
      kx += 1; if (kx >= 9) { kx -= 9; ky += 1; }
      ky += 7; if (ky >= 9) { ky -= 9; ic += 1; }
      int lkx = kx, lky = ky, loff = fixed + ic * 400 + ky * 20 + kx;
#pragma unroll
      for (int j = 0; j < 16; j++) {
        ag[j] = g_x1b[loff];
        lkx++; loff++;
        if (lkx == 9) { lkx = 0; loff += 11; lky++; if (lky == 9) { lky = 0; loff += 220; } }
      }
    }
    int k0g = ks0 + st * 64;
#pragma unroll
    for (int kk = 0; kk < 2; kk++) {
      bf16x8 bf[4];
#pragma unroll
      for (int jn = 0; jn < 4; jn++) {
        int nrow = n0 + wn * 64 + jn * 16 + c15;
        bf[jn] = *(const bf16x8*)&g_wb[(size_t)nrow * 20736 + k0g + kk * 32 + quad * 8];
      }
#pragma unroll
      for (int i = 0; i < 2; i++) {
        bf16x8 af = *(const bf16x8*)&As[(wm * 32 + i * 16 + c15) * 72 + kk * 32 + quad * 8];
#pragma unroll
        for (int jn = 0; jn < 4; jn++)
          acc[i][jn] = __builtin_amdgcn_mfma_f32_16x16x32_bf16(af, bf[jn], acc[i][jn], 0, 0, 0);
      }
    }
  }
#pragma unroll
  for (int i = 0; i < 2; i++)
#pragma unroll
    for (int jn = 0; jn < 4; jn++) {
      int col = n0 + wn * 64 + jn * 16 + c15;
#pragma unroll
      for (int rg = 0; rg < 4; rg++) {
        int row = m0 + wm * 32 + i * 16 + quad * 4 + rg;
        outp[(size_t)row * 256 + col] = acc[i][jn][rg];
      }
    }
}

// ---------------- squash primary capsules (sums 4 K-partials + bias) -------
__global__ __launch_bounds__(256) void squash_u_k(const float* __restrict__ pcb) {
  int gid = blockIdx.x * 256 + threadIdx.x;  // B*1152
  if (gid >= 256 * 1152) return;
  int b = gid / 1152;
  int n = gid - b * 1152;
  int g = n / 36;
  int s = n - g * 36;
  const float* base = g_y2p + (size_t)(b * 36 + s) * 256 + g;
  float x[8];
  float sq = 0.f;
#pragma unroll
  for (int p = 0; p < 8; p++) {
    float v = pcb[p * 32 + g] + base[p * 32] + base[PS + p * 32] +
              base[2 * PS + p * 32] + base[3 * PS + p * 32];
    x[p] = v;
    sq = fmaf(v, v, sq);
  }
  float scale = (sq / (1.f + sq)) * rsqrtf(sq + 1e-7f);
  float* uo = g_u + (size_t)gid * 8;
#pragma unroll
  for (int p = 0; p < 8; p++) uo[p] = x[p] * scale;
}

// ---------------- WU einsum ----------------
__global__ __launch_bounds__(256) void wu_k(const float* __restrict__ W) {
  __shared__ float W_s[8][161];
  __shared__ float u_s[32][8];
  int n = blockIdx.x;
  int b0 = blockIdx.y * 32;
  int t = threadIdx.x;
  const float* Wn = W + (size_t)n * 1280;
  for (int i = t; i < 1280; i += 256) {
    int cd = i >> 3, p = i & 7;
    W_s[p][cd] = Wn[i];
  }
  {
    int bl = t >> 3, p = t & 7;
    u_s[bl][p] = g_u[(size_t)(b0 + bl) * 9216 + n * 8 + p];
  }
  __syncthreads();
#pragma unroll
  for (int i = 0; i < 20; i++) {
    int idx = t + 256 * i;
    int bl = idx / 160;
    int cd = idx - bl * 160;
    float acc = 0.f;
#pragma unroll
    for (int p = 0; p < 8; p++) acc = fmaf(u_s[bl][p], W_s[p][cd], acc);
    g_WU[((size_t)(b0 + bl) * 1152 + n) * 160 + cd] = acc;
  }
}

// ---------------- iter0 reduction ----------------
__global__ __launch_bounds__(256) void red0_k() {
  int b = blockIdx.x;
  int chunk = blockIdx.y;
  int t = threadIdx.x;
  if (t >= 160) return;
  const float* base = g_WU + ((size_t)b * 1152 + chunk * 144) * 160 + t;
  float acc = 0.f;
  for (int n = 0; n < 144; n++) acc += base[(size_t)n * 160];
  atomicAdd(&g_ssum[b * 160 + t], 0.1f * acc);
}

// ---------------- squash of class capsules ----------------
__global__ void squash_v_k(int slot, float* __restrict__ clf, int write_clf) {
  int b = blockIdx.x;
  int c = threadIdx.x;
  if (c >= 10) return;
  const float* s = g_ssum + slot * 40960 + b * 160 + c * 16;
  float sq = 0.f;
#pragma unroll
  for (int d = 0; d < 16; d++) sq = fmaf(s[d], s[d], sq);
  float scale = (sq / (1.f + sq)) * rsqrtf(sq + 1e-7f);
  float* vo = g_v + slot * 40960 + b * 160 + c * 16;
#pragma unroll
  for (int d = 0; d < 16; d++) vo[d] = s[d] * scale;
  if (write_clf) clf[b * 10 + c] = scale * sqrtf(sq);
}

// ---------------- routing iteration ----------------
template <int IT>
__global__ __launch_bounds__(256) void routing_iter_k() {
  int b = blockIdx.x;
  int nb = blockIdx.y;
  int t = threadIdx.x;
  int lane = t & 15;
  int grp = t >> 4;

  const float* v0 = g_v;
  const float* v1 = g_v + 40960;
  float* ssum_out = g_ssum + IT * 40960;

  float v0r[10], v1r[10];
#pragma unroll
  for (int c = 0; c < 10; c++) v0r[c] = v0[b * 160 + c * 16 + lane];
  if (IT == 2) {
#pragma unroll
    for (int c = 0; c < 10; c++) v1r[c] = v1[b * 160 + c * 16 + lane];
  }

  float acc[10];
#pragma unroll
  for (int c = 0; c < 10; c++) acc[c] = 0.f;

  for (int ni = 0; ni < 9; ni++) {
    int n = nb * 144 + grp * 9 + ni;
    const float* row = g_WU + ((size_t)b * 1152 + n) * 160;
    float wu[10];
#pragma unroll
    for (int c = 0; c < 10; c++) wu[c] = row[c * 16 + lane];

    float bij[10];
#pragma unroll
    for (int c = 0; c < 10; c++) {
      float x = v0r[c] * wu[c];
      x += __shfl_xor(x, 1);
      x += __shfl_xor(x, 2);
      x += __shfl_xor(x, 4);
      x += __shfl_xor(x, 8);
      bij[c] = 0.1f * x;
    }

    if (IT == 2) {
      float mx = bij[0];
#pragma unroll
      for (int c = 1; c < 10; c++) mx = fmaxf(mx, bij[c]);
      float e[10], ssum = 0.f;
#pragma unroll
      for (int c = 0; c < 10; c++) {
        e[c] = __expf(bij[c] - mx);
        ssum += e[c];
      }
      float inv = 1.f / ssum;
#pragma unroll
      for (int c = 0; c < 10; c++) {
        float x = v1r[c] * wu[c];
        x += __shfl_xor(x, 1);
        x += __shfl_xor(x, 2);
        x += __shfl_xor(x, 4);
        x += __shfl_xor(x, 8);
        bij[c] = bij[c] + (e[c] * inv) * x;
      }
    }

    float mx = bij[0];
#pragma unroll
    for (int c = 1; c < 10; c++) mx = fmaxf(mx, bij[c]);
    float e[10], ssum = 0.f;
#pragma unroll
    for (int c = 0; c < 10; c++) {
      e[c] = __expf(bij[c] - mx);
      ssum += e[c];
    }
    float inv = 1.f / ssum;
#pragma unroll
    for (int c = 0; c < 10; c++) acc[c] = fmaf(e[c] * inv, wu[c], acc[c]);
  }
#pragma unroll
  for (int c = 0; c < 10; c++)
    atomicAdd(&ssum_out[b * 160 + c * 16 + lane], acc[c]);
}

// ---------------- decoder (R3: j-tiled, 4 blocks/CU latency hiding) --------
__global__ __launch_bounds__(256) void dec1_k(const int* __restrict__ labels,
                                              const float* __restrict__ w1,
                                              const float* __restrict__ b1) {
  int b = blockIdx.y;
  int j = blockIdx.x * 256 + threadIdx.x;
  int lab = labels[b];
  const float* vv = g_v + 2 * 40960 + b * 160 + lab * 16;
  float acc = b1[j];
#pragma unroll
  for (int d = 0; d < 16; d++)
    acc = fmaf(vv[d], w1[(size_t)(lab * 16 + d) * 512 + j], acc);
  g_h1[b * 512 + j] = fmaxf(acc, 0.f);
}

__global__ __launch_bounds__(256) void dec2_k(const float* __restrict__ w2,
                                              const float* __restrict__ b2) {
  __shared__ float h_s[512];
  int b = blockIdx.y;
  int j = blockIdx.x * 256 + threadIdx.x;
  int t = threadIdx.x;
  for (int i = t; i < 512; i += 256) h_s[i] = g_h1[b * 512 + i];
  __syncthreads();
  float acc = b2[j];
#pragma unroll 8
  for (int k = 0; k < 512; k++) acc = fmaf(h_s[k], w2[(size_t)k * 1024 + j], acc);
  g_h2[b * 1024 + j] = fmaxf(acc, 0.f);
}

__global__ __launch_bounds__(256) void dec3_k(const float* __restrict__ w3,
                                              const float* __restrict__ b3,
                                              float* __restrict__ out) {
  __shared__ float h_s[1024];
  int b = blockIdx.y;
  int t = threadIdx.x;
  for (int i = t; i < 1024; i += 256) h_s[i] = g_h2[b * 1024 + i];
  __syncthreads();
  if (t >= 196) return;
  int j = blockIdx.x * 196 + t;
  float acc = b3[j];
#pragma unroll 8
  for (int k = 0; k < 1024; k++) acc = fmaf(h_s[k], w3[(size_t)k * 784 + j], acc);
  out[2560 + b * 784 + j] = 1.f / (1.f + __expf(-acc));
}

// ---------------------------------------------------------------------------
extern "C" void kernel_launch(void* const* d_in, const int* in_sizes, int n_in,
                              void* d_out, int out_size, void* d_ws,
                              size_t ws_size, hipStream_t stream) {
  const float* inputs = (const float*)d_in[0];
  const int* labels = (const int*)d_in[1];
  const float* conv1_w = (const float*)d_in[2];
  const float* conv1_b = (const float*)d_in[3];
  const float* pc_w = (const float*)d_in[4];
  const float* pc_b = (const float*)d_in[5];
  const float* rw = (const float*)d_in[6];
  const float* dw1 = (const float*)d_in[7];
  const float* db1 = (const float*)d_in[8];
  const float* dw2 = (const float*)d_in[9];
  const float* db2 = (const float*)d_in[10];
  const float* dw3 = (const float*)d_in[11];
  const float* db3 = (const float*)d_in[12];
  float* out = (float*)d_out;
  (void)d_ws; (void)ws_size; (void)in_sizes; (void)n_in;

  float* y2p;
  hipGetSymbolAddress((void**)&y2p, HIP_SYMBOL(g_y2p));

  zero_ssum_k<<<(3 * 256 * 160 + 255) / 256, 256, 0, stream>>>();
  wconv_k<<<(256 * 20736 / 4 + 255) / 256, 256, 0, stream>>>(pc_w);
  conv1_relu_k<<<dim3(256, 4), 256, 0, stream>>>(inputs, conv1_w, conv1_b);
  pc_mfma_k<<<dim3(2, 144, 4), 256, 0, stream>>>(y2p);
  squash_u_k<<<1152, 256, 0, stream>>>(pc_b);
  wu_k<<<dim3(1152, 8), 256, 0, stream>>>(rw);
  red0_k<<<dim3(256, 8), 256, 0, stream>>>();
  squash_v_k<<<256, 64, 0, stream>>>(0, nullptr, 0);
  routing_iter_k<1><<<dim3(256, 8), 256, 0, stream>>>();
  squash_v_k<<<256, 64, 0, stream>>>(1, nullptr, 0);
  routing_iter_k<2><<<dim3(256, 8), 256, 0, stream>>>();
  squash_v_k<<<256, 64, 0, stream>>>(2, out, 1);
  dec1_k<<<dim3(2, 256), 256, 0, stream>>>(labels, dw1, db1);
  dec2_k<<<dim3(4, 256), 256, 0, stream>>>(dw2, db2);
  dec3_k<<<dim3(4, 256), 256, 0, stream>>>(dw3, db3, out);
}

// Round 5
// 1323.223 us; speedup vs baseline: 3.2522x; 1.0983x over previous
//
#include <hip/hip_runtime.h>
#include <math.h>

// ---------------------------------------------------------------------------
// CapsuleNet forward. R4: pc-conv A-gather vectorized via NHWC x1 layout and
// channel-innermost GEMM-k ordering (k = kp*256 + ic). conv1 emits NHWC bf16;
// wconv transposes pc_w to [oc][kp][ic]. R3 profile: pc_mfma 594us at
// MfmaUtil 6.8% — scalar 2B im2col gather was issue-bound.
// ---------------------------------------------------------------------------

typedef unsigned short u16;
typedef short bf16x8 __attribute__((ext_vector_type(8)));
typedef float f32x4 __attribute__((ext_vector_type(4)));

#define PS 2359296  // 9216*256, one y2 partial buffer

__device__ u16 g_x1b[256 * 400 * 256];          // conv1 out NHWC bf16 (52 MB)
__device__ u16 g_wb[256 * 20736];               // pc_w bf16 [oc][kp][ic]
__device__ float g_y2p[4 * PS];                 // pc GEMM K-partials (37.7 MB)
__device__ float g_u[256 * 1152 * 8];           // squashed primary caps
__device__ float g_WU[(size_t)256 * 1152 * 160];// u_hat (188.7 MB)
__device__ float g_ssum[3 * 256 * 160];
__device__ float g_v[3 * 256 * 160];
__device__ float g_h1[256 * 512];
__device__ float g_h2[256 * 1024];

__device__ __forceinline__ u16 f2bf(float f) {
  union { float f; unsigned u; } v; v.f = f;
  unsigned r = (v.u + 0x7FFFu + ((v.u >> 16) & 1u)) >> 16;  // RNE
  return (u16)r;
}

// ---------------- zero the atomic accumulators ----------------
__global__ __launch_bounds__(256) void zero_ssum_k() {
  int i = blockIdx.x * 256 + threadIdx.x;
  if (i < 3 * 256 * 160) g_ssum[i] = 0.f;
}

// ---------------- pc_w fp32 [oc][ic][kp] -> bf16 [oc][kp][ic] ----------------
__global__ __launch_bounds__(256) void wconv_k(const float* __restrict__ w) {
  __shared__ float Ws[81 * 64];   // 20.7 KB
  int oc = blockIdx.x;
  int ic0 = blockIdx.y * 64;
  int t = threadIdx.x;
  for (int idx = t; idx < 64 * 81; idx += 256) {
    int icl = idx / 81;
    int kp = idx - icl * 81;
    Ws[kp * 64 + icl] = w[(size_t)oc * 20736 + (ic0 + icl) * 81 + kp];
  }
  __syncthreads();
  for (int idx = t; idx < 81 * 64; idx += 256) {
    int kp = idx >> 6;
    int icl = idx & 63;
    g_wb[((size_t)oc * 81 + kp) * 256 + ic0 + icl] = f2bf(Ws[kp * 64 + icl]);
  }
}

// ---------------- conv1 + relu -> bf16 NHWC ----------------
__global__ __launch_bounds__(256) void conv1_relu_k(
    const float* __restrict__ in, const float* __restrict__ w,
    const float* __restrict__ bias) {
  __shared__ float in_s[784];
  __shared__ float w_s[64 * 81];
  int b = blockIdx.x;
  int oc0 = blockIdx.y * 64;
  int t = threadIdx.x;
  for (int i = t; i < 784; i += 256) in_s[i] = in[b * 784 + i];
  for (int i = t; i < 64 * 81; i += 256) w_s[i] = w[oc0 * 81 + i];
  __syncthreads();
  for (int oi = t; oi < 64 * 400; oi += 256) {
    int ocl = oi & 63;          // channel varies across lanes -> coalesced write
    int sp = oi >> 6;           // wave-uniform spatial pos -> broadcast in_s
    int oy = sp / 20;
    int ox = sp - oy * 20;
    float acc = bias[oc0 + ocl];
    const float* wr = &w_s[ocl * 81];
#pragma unroll
    for (int ky = 0; ky < 9; ky++) {
      const float* ir = &in_s[(oy + ky) * 28 + ox];
#pragma unroll
      for (int kx = 0; kx < 9; kx++) acc = fmaf(ir[kx], wr[ky * 9 + kx], acc);
    }
    // NHWC: [b][y][x][oc]
    g_x1b[(size_t)b * 102400 + sp * 256 + oc0 + ocl] = f2bf(fmaxf(acc, 0.0f));
  }
}

// ---------------- pc conv: bf16 MFMA GEMM, vectorized staging ----------------
// C[m][n] = sum_k A[m][k]*B[n][k]; k = kp*256+ic. A[m][k]=x1b[bb][2oy+ky][2ox+kx][ic],
// B = g_wb row-major. Grid (2,144,4): n0=bx*128, m0=by*64, K-slice bz*5184.
__global__ __launch_bounds__(256) void pc_mfma_k(float* __restrict__ y2p) {
  __shared__ u16 As[64 * 72];  // 64 rows x 64 k, padded row stride 72
  int t = threadIdx.x;
  int n0 = blockIdx.x * 128;
  int m0 = blockIdx.y * 64;
  int ks0 = blockIdx.z * 5184;
  float* outp = y2p + (size_t)blockIdx.z * PS;

  int w = t >> 6, l = t & 63, quad = l >> 4, c15 = l & 15;
  int wm = w & 1, wn = w >> 1;

  // A-staging: thread handles rows sr, sr+32 at 16B-column sc
  int sr = t >> 3;
  int sc = t & 7;
  int fixed0, fixed1;
  {
    int m = m0 + sr;
    int bb = m / 36;
    int s = m - bb * 36;
    int oy = s / 6;
    int ox = s - oy * 6;
    fixed0 = bb * 102400 + oy * 10240 + ox * 512 + sc * 8;
    m += 32;
    bb = m / 36;
    s = m - bb * 36;
    oy = s / 6;
    ox = s - oy * 6;
    fixed1 = bb * 102400 + oy * 10240 + ox * 512 + sc * 8;
  }

  f32x4 acc[2][4];
#pragma unroll
  for (int i = 0; i < 2; i++)
#pragma unroll
    for (int j = 0; j < 4; j++) acc[i][j] = (f32x4){0.f, 0.f, 0.f, 0.f};

  uint4 ap0, ap1;
  {
    int k0 = ks0;
    int kp = k0 >> 8, ic0 = k0 & 255;
    int ky = kp / 9, kx = kp - ky * 9;
    int off = ky * 5120 + kx * 256 + ic0;
    ap0 = *(const uint4*)(g_x1b + fixed0 + off);
    ap1 = *(const uint4*)(g_x1b + fixed1 + off);
  }

  for (int st = 0; st < 81; st++) {
    __syncthreads();
    *(uint4*)&As[sr * 72 + sc * 8] = ap0;
    *(uint4*)&As[(sr + 32) * 72 + sc * 8] = ap1;
    __syncthreads();
    if (st < 80) {
      int k0 = ks0 + (st + 1) * 64;
      int kp = k0 >> 8, ic0 = k0 & 255;
      int ky = kp / 9, kx = kp - ky * 9;
      int off = ky * 5120 + kx * 256 + ic0;
      ap0 = *(const uint4*)(g_x1b + fixed0 + off);
      ap1 = *(const uint4*)(g_x1b + fixed1 + off);
    }
    int k0g = ks0 + st * 64;
#pragma unroll
    for (int kk = 0; kk < 2; kk++) {
      bf16x8 bfr[4];
#pragma unroll
      for (int jn = 0; jn < 4; jn++) {
        int nrow = n0 + wn * 64 + jn * 16 + c15;
        bfr[jn] = *(const bf16x8*)&g_wb[(size_t)nrow * 20736 + k0g + kk * 32 + quad * 8];
      }
#pragma unroll
      for (int i = 0; i < 2; i++) {
        bf16x8 af = *(const bf16x8*)&As[(wm * 32 + i * 16 + c15) * 72 + kk * 32 + quad * 8];
#pragma unroll
        for (int jn = 0; jn < 4; jn++)
          acc[i][jn] = __builtin_amdgcn_mfma_f32_16x16x32_bf16(af, bfr[jn], acc[i][jn], 0, 0, 0);
      }
    }
  }
  // epilogue: C/D map col=lane&15, row=quad*4+reg
#pragma unroll
  for (int i = 0; i < 2; i++)
#pragma unroll
    for (int jn = 0; jn < 4; jn++) {
      int col = n0 + wn * 64 + jn * 16 + c15;
#pragma unroll
      for (int rg = 0; rg < 4; rg++) {
        int row = m0 + wm * 32 + i * 16 + quad * 4 + rg;
        outp[(size_t)row * 256 + col] = acc[i][jn][rg];
      }
    }
}

// ---------------- squash primary capsules (sums 4 K-partials + bias) -------
__global__ __launch_bounds__(256) void squash_u_k(const float* __restrict__ pcb) {
  int gid = blockIdx.x * 256 + threadIdx.x;  // B*1152
  if (gid >= 256 * 1152) return;
  int b = gid / 1152;
  int n = gid - b * 1152;
  int g = n / 36;
  int s = n - g * 36;
  const float* base = g_y2p + (size_t)(b * 36 + s) * 256 + g;
  float x[8];
  float sq = 0.f;
#pragma unroll
  for (int p = 0; p < 8; p++) {
    float v = pcb[p * 32 + g] + base[p * 32] + base[PS + p * 32] +
              base[2 * PS + p * 32] + base[3 * PS + p * 32];
    x[p] = v;
    sq = fmaf(v, v, sq);
  }
  float scale = (sq / (1.f + sq)) * rsqrtf(sq + 1e-7f);
  float* uo = g_u + (size_t)gid * 8;
#pragma unroll
  for (int p = 0; p < 8; p++) uo[p] = x[p] * scale;
}

// ---------------- WU einsum ----------------
__global__ __launch_bounds__(256) void wu_k(const float* __restrict__ W) {
  __shared__ float W_s[8][161];
  __shared__ float u_s[32][8];
  int n = blockIdx.x;
  int b0 = blockIdx.y * 32;
  int t = threadIdx.x;
  const float* Wn = W + (size_t)n * 1280;
  for (int i = t; i < 1280; i += 256) {
    int cd = i >> 3, p = i & 7;
    W_s[p][cd] = Wn[i];
  }
  {
    int bl = t >> 3, p = t & 7;
    u_s[bl][p] = g_u[(size_t)(b0 + bl) * 9216 + n * 8 + p];
  }
  __syncthreads();
#pragma unroll
  for (int i = 0; i < 20; i++) {
    int idx = t + 256 * i;
    int bl = idx / 160;
    int cd = idx - bl * 160;
    float acc = 0.f;
#pragma unroll
    for (int p = 0; p < 8; p++) acc = fmaf(u_s[bl][p], W_s[p][cd], acc);
    g_WU[((size_t)(b0 + bl) * 1152 + n) * 160 + cd] = acc;
  }
}

// ---------------- iter0 reduction ----------------
__global__ __launch_bounds__(256) void red0_k() {
  int b = blockIdx.x;
  int chunk = blockIdx.y;
  int t = threadIdx.x;
  if (t >= 160) return;
  const float* base = g_WU + ((size_t)b * 1152 + chunk * 144) * 160 + t;
  float acc = 0.f;
  for (int n = 0; n < 144; n++) acc += base[(size_t)n * 160];
  atomicAdd(&g_ssum[b * 160 + t], 0.1f * acc);
}

// ---------------- squash of class capsules ----------------
__global__ void squash_v_k(int slot, float* __restrict__ clf, int write_clf) {
  int b = blockIdx.x;
  int c = threadIdx.x;
  if (c >= 10) return;
  const float* s = g_ssum + slot * 40960 + b * 160 + c * 16;
  float sq = 0.f;
#pragma unroll
  for (int d = 0; d < 16; d++) sq = fmaf(s[d], s[d], sq);
  float scale = (sq / (1.f + sq)) * rsqrtf(sq + 1e-7f);
  float* vo = g_v + slot * 40960 + b * 160 + c * 16;
#pragma unroll
  for (int d = 0; d < 16; d++) vo[d] = s[d] * scale;
  if (write_clf) clf[b * 10 + c] = scale * sqrtf(sq);
}

// ---------------- routing iteration ----------------
template <int IT>
__global__ __launch_bounds__(256) void routing_iter_k() {
  int b = blockIdx.x;
  int nb = blockIdx.y;
  int t = threadIdx.x;
  int lane = t & 15;
  int grp = t >> 4;

  const float* v0 = g_v;
  const float* v1 = g_v + 40960;
  float* ssum_out = g_ssum + IT * 40960;

  float v0r[10], v1r[10];
#pragma unroll
  for (int c = 0; c < 10; c++) v0r[c] = v0[b * 160 + c * 16 + lane];
  if (IT == 2) {
#pragma unroll
    for (int c = 0; c < 10; c++) v1r[c] = v1[b * 160 + c * 16 + lane];
  }

  float acc[10];
#pragma unroll
  for (int c = 0; c < 10; c++) acc[c] = 0.f;

  for (int ni = 0; ni < 9; ni++) {
    int n = nb * 144 + grp * 9 + ni;
    const float* row = g_WU + ((size_t)b * 1152 + n) * 160;
    float wu[10];
#pragma unroll
    for (int c = 0; c < 10; c++) wu[c] = row[c * 16 + lane];

    float bij[10];
#pragma unroll
    for (int c = 0; c < 10; c++) {
      float x = v0r[c] * wu[c];
      x += __shfl_xor(x, 1);
      x += __shfl_xor(x, 2);
      x += __shfl_xor(x, 4);
      x += __shfl_xor(x, 8);
      bij[c] = 0.1f * x;
    }

    if (IT == 2) {
      float mx = bij[0];
#pragma unroll
      for (int c = 1; c < 10; c++) mx = fmaxf(mx, bij[c]);
      float e[10], ssum = 0.f;
#pragma unroll
      for (int c = 0; c < 10; c++) {
        e[c] = __expf(bij[c] - mx);
        ssum += e[c];
      }
      float inv = 1.f / ssum;
#pragma unroll
      for (int c = 0; c < 10; c++) {
        float x = v1r[c] * wu[c];
        x += __shfl_xor(x, 1);
        x += __shfl_xor(x, 2);
        x += __shfl_xor(x, 4);
        x += __shfl_xor(x, 8);
        bij[c] = bij[c] + (e[c] * inv) * x;
      }
    }

    float mx = bij[0];
#pragma unroll
    for (int c = 1; c < 10; c++) mx = fmaxf(mx, bij[c]);
    float e[10], ssum = 0.f;
#pragma unroll
    for (int c = 0; c < 10; c++) {
      e[c] = __expf(bij[c] - mx);
      ssum += e[c];
    }
    float inv = 1.f / ssum;
#pragma unroll
    for (int c = 0; c < 10; c++) acc[c] = fmaf(e[c] * inv, wu[c], acc[c]);
  }
#pragma unroll
  for (int c = 0; c < 10; c++)
    atomicAdd(&ssum_out[b * 160 + c * 16 + lane], acc[c]);
}

// ---------------- decoder (j-tiled, 4 blocks/CU latency hiding) --------
__global__ __launch_bounds__(256) void dec1_k(const int* __restrict__ labels,
                                              const float* __restrict__ w1,
                                              const float* __restrict__ b1) {
  int b = blockIdx.y;
  int j = blockIdx.x * 256 + threadIdx.x;
  int lab = labels[b];
  const float* vv = g_v + 2 * 40960 + b * 160 + lab * 16;
  float acc = b1[j];
#pragma unroll
  for (int d = 0; d < 16; d++)
    acc = fmaf(vv[d], w1[(size_t)(lab * 16 + d) * 512 + j], acc);
  g_h1[b * 512 + j] = fmaxf(acc, 0.f);
}

__global__ __launch_bounds__(256) void dec2_k(const float* __restrict__ w2,
                                              const float* __restrict__ b2) {
  __shared__ float h_s[512];
  int b = blockIdx.y;
  int j = blockIdx.x * 256 + threadIdx.x;
  int t = threadIdx.x;
  for (int i = t; i < 512; i += 256) h_s[i] = g_h1[b * 512 + i];
  __syncthreads();
  float acc = b2[j];
#pragma unroll 8
  for (int k = 0; k < 512; k++) acc = fmaf(h_s[k], w2[(size_t)k * 1024 + j], acc);
  g_h2[b * 1024 + j] = fmaxf(acc, 0.f);
}

__global__ __launch_bounds__(256) void dec3_k(const float* __restrict__ w3,
                                              const float* __restrict__ b3,
                                              float* __restrict__ out) {
  __shared__ float h_s[1024];
  int b = blockIdx.y;
  int t = threadIdx.x;
  for (int i = t; i < 1024; i += 256) h_s[i] = g_h2[b * 1024 + i];
  __syncthreads();
  if (t >= 196) return;
  int j = blockIdx.x * 196 + t;
  float acc = b3[j];
#pragma unroll 8
  for (int k = 0; k < 1024; k++) acc = fmaf(h_s[k], w3[(size_t)k * 784 + j], acc);
  out[2560 + b * 784 + j] = 1.f / (1.f + __expf(-acc));
}

// ---------------------------------------------------------------------------
extern "C" void kernel_launch(void* const* d_in, const int* in_sizes, int n_in,
                              void* d_out, int out_size, void* d_ws,
                              size_t ws_size, hipStream_t stream) {
  const float* inputs = (const float*)d_in[0];
  const int* labels = (const int*)d_in[1];
  const float* conv1_w = (const float*)d_in[2];
  const float* conv1_b = (const float*)d_in[3];
  const float* pc_w = (const float*)d_in[4];
  const float* pc_b = (const float*)d_in[5];
  const float* rw = (const float*)d_in[6];
  const float* dw1 = (const float*)d_in[7];
  const float* db1 = (const float*)d_in[8];
  const float* dw2 = (const float*)d_in[9];
  const float* db2 = (const float*)d_in[10];
  const float* dw3 = (const float*)d_in[11];
  const float* db3 = (const float*)d_in[12];
  float* out = (float*)d_out;
  (void)d_ws; (void)ws_size; (void)in_sizes; (void)n_in;

  float* y2p;
  hipGetSymbolAddress((void**)&y2p, HIP_SYMBOL(g_y2p));

  zero_ssum_k<<<(3 * 256 * 160 + 255) / 256, 256, 0, stream>>>();
  wconv_k<<<dim3(256, 4), 256, 0, stream>>>(pc_w);
  conv1_relu_k<<<dim3(256, 4), 256, 0, stream>>>(inputs, conv1_w, conv1_b);
  pc_mfma_k<<<dim3(2, 144, 4), 256, 0, stream>>>(y2p);
  squash_u_k<<<1152, 256, 0, stream>>>(pc_b);
  wu_k<<<dim3(1152, 8), 256, 0, stream>>>(rw);
  red0_k<<<dim3(256, 8), 256, 0, stream>>>();
  squash_v_k<<<256, 64, 0, stream>>>(0, nullptr, 0);
  routing_iter_k<1><<<dim3(256, 8), 256, 0, stream>>>();
  squash_v_k<<<256, 64, 0, stream>>>(1, nullptr, 0);
  routing_iter_k<2><<<dim3(256, 8), 256, 0, stream>>>();
  squash_v_k<<<256, 64, 0, stream>>>(2, out, 1);
  dec1_k<<<dim3(2, 256), 256, 0, stream>>>(labels, dw1, db1);
  dec2_k<<<dim3(4, 256), 256, 0, stream>>>(dw2, db2);
  dec3_k<<<dim3(4, 256), 256, 0, stream>>>(dw3, db3, out);
}